// Round 13
// baseline (153.245 us; speedup 1.0000x reference)
//
#include <hip/hip_runtime.h>
#include <math.h>

#define B_ 64
#define NV_ 256
#define N_ 768
#define NNZ 8          // fixed-width sparse row: real max nnz is 6; pads are (col=i, val=0)
#define M_ (B_ * N_)   // 49152 rows

typedef unsigned short us8 __attribute__((ext_vector_type(8)));
typedef unsigned short us4 __attribute__((ext_vector_type(4)));
typedef __bf16 bf16x8 __attribute__((ext_vector_type(8)));
typedef float f32x4 __attribute__((ext_vector_type(4)));

__device__ inline float bf2f(unsigned short u) {
    return __uint_as_float(((unsigned int)u) << 16);
}
__device__ inline unsigned short f2bf(float f) {
    unsigned int u = __float_as_uint(f);
    unsigned int r = u + 0x7fffu + ((u >> 16) & 1u);
    return (unsigned short)(r >> 16);
}
__device__ inline bf16x8 ld_bf8(const unsigned short* p) {
    us8 u = *(const us8*)p;
    return __builtin_bit_cast(bf16x8, u);
}

struct GP {
    const float *x, *inputs, *A, *W1, *b1, *W2, *b2, *W3, *b3, *W4, *b4;
    const int *psel, *c1s, *c2s;
    int np, n1, n2;
    float* dinv;
    float* rowsum;
    int* clampf;
    int* cols;
    float* vals;
    unsigned short* W2b;
    unsigned short* W3b;
    float* S;
    unsigned short* T2;
    unsigned int* bar;   // 4 barrier slots, zeroed via hipMemsetAsync before launch
    float* out;
};

// grid barrier: arrival count per slot; device-scope fences for cross-XCD visibility.
// Grid is sized by the occupancy query, so all blocks are co-resident by construction.
// Cycle-bounded spin (~80ms) as an anti-hang safety valve only.
__device__ __forceinline__ void gsync(unsigned int* bar, int slot) {
    __syncthreads();
    if (threadIdx.x == 0) {
        __threadfence();                      // release: drain + make writes visible
        atomicAdd(&bar[slot], 1u);
        unsigned int nb = gridDim.x;
        long long t0 = clock64();
        while (atomicAdd(&bar[slot], 0u) < nb) {
            __builtin_amdgcn_s_sleep(16);
            if (clock64() - t0 > 200000000LL) break;
        }
        __threadfence();                      // acquire: invalidate stale L1/L2
    }
    __syncthreads();
}

__global__ __launch_bounds__(256) void k_mega(GP p) {
    int tid = threadIdx.x, blk = blockIdx.x;
    int gd = gridDim.x;
    int wave = tid >> 6, lane = tid & 63;
    int lrow = lane & 15, kgrp = lane >> 4;

    __shared__ union {
        struct { int wc[4][NNZ]; float wa[4][NNZ]; } sp;
        struct { float Xs[64][6]; float W1T[6][256]; float b1s[256]; } l12;
        struct { float W4s[384]; } l3;
    } sm;

    // ---------- Phase A: degrees + raw compacted rows / W->bf16 / clamp flags ----------
    for (int vb = blk; vb < 385; vb += gd) {
        if (vb < 192) {
            int i = vb * 4 + wave;
            float deg = 0.f;
            int cnt = 0;
#pragma unroll
            for (int c0 = 0; c0 < N_; c0 += 64) {
                float a = p.A[(size_t)i * N_ + c0 + lane];
                deg += a;
                unsigned long long m = __ballot(a != 0.f);
                if (a != 0.f) {
                    int pos = cnt + __popcll(m & ((1ull << lane) - 1ull));
                    if (pos < NNZ) {
                        sm.sp.wc[wave][pos] = c0 + lane;
                        sm.sp.wa[wave][pos] = a;
                    }
                }
                cnt += (int)__popcll(m);
            }
#pragma unroll
            for (int o = 32; o > 0; o >>= 1) deg += __shfl_xor(deg, o);
            __syncthreads();
            int nn = cnt < NNZ ? cnt : NNZ;
            if (lane < NNZ) {
                p.cols[i * NNZ + lane] = (lane < nn) ? sm.sp.wc[wave][lane] : i;
                p.vals[i * NNZ + lane] = (lane < nn) ? sm.sp.wa[wave][lane] : 0.f;  // raw a
            }
            if (lane == 0) p.dinv[i] = (deg == 0.f) ? 0.f : 1.0f / sqrtf(deg);
        } else if (vb < 384) {
            int idx = (vb - 192) * 256 + tid;
            if (idx < 32768) p.W2b[idx] = f2bf(p.W2[idx]);
            else p.W3b[idx - 32768] = f2bf(p.W3[idx - 32768]);
        } else {
            p.clampf[tid] = 0;
            p.clampf[tid + 256] = 0;
            p.clampf[tid + 512] = 0;
            __syncthreads();
            if (tid < p.np) p.clampf[p.psel[tid]] = 1;
            else if (tid - p.np < p.n1) p.clampf[NV_ + p.c1s[tid - p.np]] = 1;
            else if (tid - p.np - p.n1 < p.n2)
                p.clampf[2 * NV_ + p.c2s[tid - p.np - p.n1]] = 1;
        }
        __syncthreads();   // protect LDS reuse across virtual blocks
    }
    gsync(p.bar, 0);

    // ---------- Phase B: normalize vals in place + rowsum ----------
    for (int idx = blk * 256 + tid; idx < N_ * NNZ; idx += gd * 256) {
        int i = idx >> 3;
        int c = p.cols[idx];
        float v = p.vals[idx] * p.dinv[i] * p.dinv[c];
        p.vals[idx] = v;
        float rs = v;
        rs += __shfl_xor(rs, 1);
        rs += __shfl_xor(rs, 2);
        rs += __shfl_xor(rs, 4);
        if ((idx & 7) == 0) p.rowsum[i] = rs;
    }
    gsync(p.bar, 1);

    // ---------- Phase C: layer12 — agg(F=6) -> 6->256 linear+relu -> MFMA 256->128 ----------
    for (int t = tid; t < 1536; t += 256) {
        int k = t >> 8, c = t & 255;
        sm.l12.W1T[k][c] = p.W1[c * 6 + k];
    }
    sm.l12.b1s[tid] = p.b1[tid];

    for (int vb = blk; vb < 768; vb += gd) {
        int i0 = (vb % 12) * 64;
        int base = (vb / 12) * N_;
        __syncthreads();   // Xs reuse guard + W1T ready on first iter

        for (int t = lane; t < 96; t += 64) {
            int f = t % 6, ro = t / 6;
            int i = i0 + wave * 16 + ro;
            float s = 0.f;
#pragma unroll
            for (int k = 0; k < NNZ; ++k) {
                int c = p.cols[i * NNZ + k];
                float v = p.vals[i * NNZ + k];
                float val = (f < 3 && p.clampf[c]) ? p.inputs[(size_t)(base + c) * 3 + f]
                                                   : p.x[(size_t)(base + c) * 6 + f];
                s += v * val;
            }
            sm.l12.Xs[wave * 16 + ro][f] = s;
        }
        __syncthreads();

        int i = i0 + wave * 16 + lrow;
        size_t g = (size_t)(base + i);
        float rs = p.rowsum[i];
        float xa[6];
#pragma unroll
        for (int k = 0; k < 6; ++k) xa[k] = sm.l12.Xs[wave * 16 + lrow][k];

        f32x4 acc[8];
#pragma unroll
        for (int j = 0; j < 8; ++j) acc[j] = (f32x4){0.f, 0.f, 0.f, 0.f};

#pragma unroll
        for (int s = 0; s < 8; ++s) {
            int c0 = s * 32 + kgrp * 8;
            float h[8];
            f32x4 bv0 = *(const f32x4*)&sm.l12.b1s[c0];
            f32x4 bv1 = *(const f32x4*)&sm.l12.b1s[c0 + 4];
#pragma unroll
            for (int e = 0; e < 4; ++e) {
                h[e] = rs * bv0[e];
                h[4 + e] = rs * bv1[e];
            }
#pragma unroll
            for (int k = 0; k < 6; ++k) {
                f32x4 w0 = *(const f32x4*)&sm.l12.W1T[k][c0];
                f32x4 w1 = *(const f32x4*)&sm.l12.W1T[k][c0 + 4];
#pragma unroll
                for (int e = 0; e < 4; ++e) {
                    h[e] += xa[k] * w0[e];
                    h[4 + e] += xa[k] * w1[e];
                }
            }
            us8 o;
#pragma unroll
            for (int e = 0; e < 8; ++e) o[e] = f2bf(fmaxf(h[e], 0.f));
            bf16x8 af = __builtin_bit_cast(bf16x8, o);
#pragma unroll
            for (int j = 0; j < 8; ++j) {
                bf16x8 w = ld_bf8(p.W2b + (size_t)(j * 16 + lrow) * 256 + c0);
                acc[j] = __builtin_amdgcn_mfma_f32_16x16x32_bf16(w, af, acc[j], 0, 0, 0);
            }
        }

#pragma unroll
        for (int j = 0; j < 8; ++j) {
            f32x4 bv = *(const f32x4*)&p.b2[j * 16 + kgrp * 4];
            us4 o;
#pragma unroll
            for (int e = 0; e < 4; ++e) o[e] = f2bf(acc[j][e] + bv[e]);
            *(us4*)(p.T2 + g * 128 + j * 16 + kgrp * 4) = o;
        }
    }
    gsync(p.bar, 2);

    // ---------- Phase D: layer3s — relu(agg(T2)) -> MFMA 128->128 -> S = T3row @ W4^T ----------
    for (int t = tid; t < 384; t += 256) {
        int d = t % 3, nfeat = t / 3;
        sm.l3.W4s[t] = p.W4[d * 128 + nfeat];
    }
    __syncthreads();

    for (int vb = blk; vb < 768; vb += gd) {
        int i0 = (vb % 12) * 64;
        int base = (vb / 12) * N_;
        int i = i0 + wave * 16 + lrow;
        size_t g = (size_t)(base + i);

        float fa[4][8];
#pragma unroll
        for (int s = 0; s < 4; ++s)
#pragma unroll
            for (int e = 0; e < 8; ++e) fa[s][e] = 0.f;

#pragma unroll
        for (int k = 0; k < NNZ; ++k) {
            int c = p.cols[i * NNZ + k];
            float v = p.vals[i * NNZ + k];
            const unsigned short* pt = p.T2 + (size_t)(base + c) * 128 + kgrp * 8;
#pragma unroll
            for (int s = 0; s < 4; ++s) {
                us8 z = *(const us8*)(pt + s * 32);
#pragma unroll
                for (int e = 0; e < 8; ++e) fa[s][e] += v * bf2f(z[e]);
            }
        }

        bf16x8 af[4];
#pragma unroll
        for (int s = 0; s < 4; ++s) {
            us8 o;
#pragma unroll
            for (int e = 0; e < 8; ++e) o[e] = f2bf(fmaxf(fa[s][e], 0.f));
            af[s] = __builtin_bit_cast(bf16x8, o);
        }

        f32x4 acc[8];
#pragma unroll
        for (int j = 0; j < 8; ++j) acc[j] = (f32x4){0.f, 0.f, 0.f, 0.f};
#pragma unroll
        for (int s = 0; s < 4; ++s) {
#pragma unroll
            for (int j = 0; j < 8; ++j) {
                bf16x8 w = ld_bf8(p.W3b + (size_t)(j * 16 + lrow) * 128 + s * 32 + kgrp * 8);
                acc[j] = __builtin_amdgcn_mfma_f32_16x16x32_bf16(w, af[s], acc[j], 0, 0, 0);
            }
        }

        float s0 = 0.f, s1 = 0.f, s2 = 0.f;
#pragma unroll
        for (int j = 0; j < 8; ++j) {
            f32x4 bv = *(const f32x4*)&p.b3[j * 16 + kgrp * 4];
#pragma unroll
            for (int e = 0; e < 4; ++e) {
                float tv = acc[j][e] + bv[e];
                int nfeat = j * 16 + kgrp * 4 + e;
                s0 += tv * sm.l3.W4s[nfeat * 3 + 0];
                s1 += tv * sm.l3.W4s[nfeat * 3 + 1];
                s2 += tv * sm.l3.W4s[nfeat * 3 + 2];
            }
        }
        s0 += __shfl_xor(s0, 16); s0 += __shfl_xor(s0, 32);
        s1 += __shfl_xor(s1, 16); s1 += __shfl_xor(s1, 32);
        s2 += __shfl_xor(s2, 16); s2 += __shfl_xor(s2, 32);
        if (kgrp == 0) {
            p.S[g * 3 + 0] = s0;
            p.S[g * 3 + 1] = s1;
            p.S[g * 3 + 2] = s2;
        }
    }
    gsync(p.bar, 3);

    // ---------- Phase E: out = A*(A*S) + rowsum*b4, with output clamp ----------
    for (int idx = blk * 256 + tid; idx < M_ * 3; idx += gd * 256) {
        int f = idx % 3;
        int r = idx / 3;
        int i = r % N_;
        int base = r - i;
        if (p.clampf[i]) {
            p.out[idx] = p.inputs[(size_t)r * 3 + f];
        } else {
            float s = p.rowsum[i] * p.b4[f];
#pragma unroll
            for (int k = 0; k < NNZ; ++k) {
                int c = p.cols[i * NNZ + k];
                float vik = p.vals[i * NNZ + k];
                float u = 0.f;
#pragma unroll
                for (int q = 0; q < NNZ; ++q) {
                    int j = p.cols[c * NNZ + q];
                    u += p.vals[c * NNZ + q] * p.S[(size_t)(base + j) * 3 + f];
                }
                s += vik * u;
            }
            p.out[idx] = s;
        }
    }
}

// ---------------- launch ----------------

extern "C" void kernel_launch(void* const* d_in, const int* in_sizes, int n_in,
                              void* d_out, int out_size, void* d_ws, size_t ws_size,
                              hipStream_t stream) {
    char* ws = (char*)d_ws;
    GP p;
    p.x      = (const float*)d_in[0];
    p.inputs = (const float*)d_in[1];
    p.A      = (const float*)d_in[2];
    p.W1     = (const float*)d_in[3];
    p.b1     = (const float*)d_in[4];
    p.W2     = (const float*)d_in[5];
    p.b2     = (const float*)d_in[6];
    p.W3     = (const float*)d_in[7];
    p.b3     = (const float*)d_in[8];
    p.W4     = (const float*)d_in[9];
    p.b4     = (const float*)d_in[10];
    p.psel   = (const int*)d_in[11];
    p.c1s    = (const int*)d_in[12];
    p.c2s    = (const int*)d_in[13];
    p.np = in_sizes[11];
    p.n1 = in_sizes[12];
    p.n2 = in_sizes[13];
    p.dinv   = (float*)(ws + 0);
    p.rowsum = (float*)(ws + 3072);
    p.clampf = (int*)(ws + 9216);
    p.cols   = (int*)(ws + 12288);
    p.vals   = (float*)(ws + 61440);
    p.W2b    = (unsigned short*)(ws + 110592);
    p.W3b    = (unsigned short*)(ws + 176128);
    p.bar    = (unsigned int*)(ws + 212992);
    p.S      = (float*)(ws + 417792);
    p.T2     = (unsigned short*)(ws + 27144192);
    p.out    = (float*)d_out;

    // grid sized by queried occupancy -> all blocks co-resident by construction
    int bpc = 0;
    hipError_t e = hipOccupancyMaxActiveBlocksPerMultiprocessor(&bpc, k_mega, 256, 0);
    if (e != hipSuccess || bpc < 1) bpc = 1;
    int grid = bpc * 256;          // 256 CUs on MI355X
    if (grid > 768) grid = 768;

    hipMemsetAsync(p.bar, 0, 16, stream);
    k_mega<<<grid, 256, 0, stream>>>(p);
}